// Round 1
// baseline (292.363 us; speedup 1.0000x reference)
//
#include <hip/hip_runtime.h>

typedef __bf16 bf16x8 __attribute__((ext_vector_type(8)));
typedef float  f32x4  __attribute__((ext_vector_type(4)));
typedef unsigned short u16x8 __attribute__((ext_vector_type(8)));

// Problem constants
constexpr int BB    = 16;
constexpr int TT    = 12;
constexpr int NN    = 307;
constexpr int TN    = TT * NN;        // 3684
constexpr int ROWSX = BB * TT * NN;   // 58944
constexpr int ROWSH = BB * NN;        // 4912
constexpr int SST1  = 3712;           // sag row stride (464 x b128 chunks)
constexpr int SSTR  = 3840;           // xnT row stride
constexpr float SCALE = 0.125f;

__device__ __forceinline__ float wred_sum(float v) {
#pragma unroll
    for (int m = 32; m > 0; m >>= 1) v += __shfl_xor(v, m, 64);
    return v;
}

// ---------------------------------------------------------------------------
// Fold q/k projections: dg = q.k = qt.x_ + c
// ---------------------------------------------------------------------------
__global__ void fold_k(const float* __restrict__ qw, const float* __restrict__ qb,
                       const float* __restrict__ kw, const float* __restrict__ kb,
                       float* __restrict__ M, float* __restrict__ b2,
                       float* __restrict__ vv, float* __restrict__ cc) {
    int e = blockIdx.x, d = threadIdx.x;
    float acc = 0.f;
    for (int dp = 0; dp < 64; ++dp) acc += qw[dp * 64 + e] * kw[dp * 64 + d];
    M[e * 64 + d] = acc;
    float vp = wred_sum(qw[d * 64 + e] * kb[d]);
    if (d == 0) vv[e] = vp;
    if (e == 0) {
        float b = 0.f;
        for (int dp = 0; dp < 64; ++dp) b += qb[dp] * kw[dp * 64 + d];
        b2[d] = b;
        float cp = wred_sum(qb[d] * kb[d]);
        if (d == 0) *cc = cp;
    }
}

// ---------------------------------------------------------------------------
// fc1w/fc2w fp32 -> bf16
// ---------------------------------------------------------------------------
__global__ void wconv_k(const float* __restrict__ fc1w, const float* __restrict__ fc2w,
                        __bf16* __restrict__ fc1b16, __bf16* __restrict__ fc2b16) {
    int i = blockIdx.x * 256 + threadIdx.x;
    if (i < 16384) fc1b16[i] = (__bf16)fc1w[i];
    else fc2b16[i - 16384] = (__bf16)fc2w[i - 16384];
}

// ---------------------------------------------------------------------------
// LayerNorm -> xnb (bf16) + y32 (fp32, t==11 slab)
// ---------------------------------------------------------------------------
__global__ __launch_bounds__(256) void ln_k(const float* __restrict__ x,
                                            const float* __restrict__ g,
                                            const float* __restrict__ b,
                                            __bf16* __restrict__ xnb,
                                            float* __restrict__ y32) {
    int w = threadIdx.x >> 6, l = threadIdx.x & 63;
    int r = blockIdx.x * 4 + w;
    if (r >= ROWSX) return;
    float val = x[r * 64 + l];
    float mu  = wred_sum(val) * (1.f / 64.f);
    float dv  = val - mu;
    float var = wred_sum(dv * dv) * (1.f / 64.f);
    float xv  = dv * rsqrtf(var + 1e-5f) * g[l] + b[l];
    xnb[(size_t)r * 64 + l] = (__bf16)xv;
    int t = (r / NN) % TT;
    if (t == TT - 1) {
        int bbv = r / (NN * TT), n = r % NN;
        y32[(bbv * NN + n) * 64 + l] = xv;
    }
}

// ---------------------------------------------------------------------------
// Transpose xnb[b,j,d] -> xnT[b,d,j] (stride SSTR; j>=TN zero within tiles)
// ---------------------------------------------------------------------------
__global__ __launch_bounds__(256) void t_k(const __bf16* __restrict__ xnb,
                                           __bf16* __restrict__ xnT) {
    __shared__ unsigned short tile[64][65];
    int bb = blockIdx.y, j0 = blockIdx.x * 64, t = threadIdx.x;
    const unsigned short* src = (const unsigned short*)xnb;
    unsigned short* dst = (unsigned short*)xnT;
#pragma unroll
    for (int i = 0; i < 16; ++i) {
        int f = t + 256 * i, jr = f >> 6, dc = f & 63;
        int j = j0 + jr;
        tile[jr][dc] = (j < TN) ? src[((size_t)bb * TN + j) * 64 + dc] : (unsigned short)0;
    }
    __syncthreads();
#pragma unroll
    for (int i = 0; i < 16; ++i) {
        int f = t + 256 * i, d = f >> 6, jj = f & 63;
        dst[((size_t)bb * 64 + d) * SSTR + j0 + jj] = tile[jj][d];
    }
}

// ---------------------------------------------------------------------------
// qt[row] = y_ @ M + b2 (bf16);  cq[row] = y_.v + cc
// ---------------------------------------------------------------------------
__global__ __launch_bounds__(256) void qt_k(const float* __restrict__ y32,
                                            const float* __restrict__ M,
                                            const float* __restrict__ b2,
                                            const float* __restrict__ vv,
                                            const float* __restrict__ ccp,
                                            __bf16* __restrict__ qtb,
                                            float* __restrict__ cq) {
    int w = threadIdx.x >> 6, l = threadIdx.x & 63;
    int rr = blockIdx.x * 4 + w;
    if (rr >= ROWSH) return;
    float y = y32[rr * 64 + l];
    float acc = b2[l];
#pragma unroll
    for (int e = 0; e < 64; ++e) acc += __shfl(y, e, 64) * M[e * 64 + l];
    qtb[(size_t)rr * 64 + l] = (__bf16)acc;
    float cp = wred_sum(y * vv[l]);
    if (l == 0) cq[rr] = cp + *ccp;
}

// ---------------------------------------------------------------------------
// Score GEMM via MFMA. stg staged via LDS float4. Epilogue computes bf16
// weights into registers, transposes through LDS (overlaying sstg), then
// stores coalesced b128.
// ---------------------------------------------------------------------------
__global__ __launch_bounds__(256) void score_k(const __bf16* __restrict__ qtb,
                                               const float* __restrict__ cq,
                                               const __bf16* __restrict__ xnb,
                                               const float* __restrict__ stg,
                                               __bf16* __restrict__ sag) {
    __shared__ float sstg[64 * 132];   // 33 KB; phase-2 overlay: u16 wb[64][136]
    int bb = blockIdx.z, n0 = blockIdx.y * 64, j0 = blockIdx.x * 128;
    int t = threadIdx.x;
    int w = t >> 6, lane = t & 63;
    int m16 = lane & 15, q4 = lane >> 4;

    // ---- stage stg tile [64n x 128j] fp32 -> LDS (coalesced float4) ----
#pragma unroll
    for (int i = 0; i < 8; ++i) {
        int flat = t + i * 256;
        int row = flat >> 5, c4 = (flat & 31) * 4;
        int n = n0 + row;
        float4 v = {0.f, 0.f, 0.f, 0.f};
        if (n < NN) {
            size_t rb = (size_t)(bb * NN + n) * TN;
            int j = j0 + c4;
            if (j + 3 < TN) v = *(const float4*)(stg + rb + j);
            else {
                if (j + 0 < TN) v.x = stg[rb + j + 0];
                if (j + 1 < TN) v.y = stg[rb + j + 1];
                if (j + 2 < TN) v.z = stg[rb + j + 2];
                if (j + 3 < TN) v.w = stg[rb + j + 3];
            }
        }
        *(float4*)&sstg[row * 132 + c4] = v;
    }

    // ---- MFMA: 64n x 128j, K=64 ----
    const bf16x8* ap = (const bf16x8*)(qtb + ((size_t)bb * NN + n0 + w * 16 + m16) * 64);
    bf16x8 a0 = ap[q4], a1 = ap[q4 + 4];
    f32x4 acc[8];
#pragma unroll
    for (int jt = 0; jt < 8; ++jt) {
        const bf16x8* bp = (const bf16x8*)(xnb + ((size_t)bb * TN + j0 + jt * 16 + m16) * 64);
        bf16x8 b0 = bp[q4], b1 = bp[q4 + 4];
        f32x4 c = {0.f, 0.f, 0.f, 0.f};
        c = __builtin_amdgcn_mfma_f32_16x16x32_bf16(a0, b0, c, 0, 0, 0);
        c = __builtin_amdgcn_mfma_f32_16x16x32_bf16(a1, b1, c, 0, 0, 0);
        acc[jt] = c;
    }
    int nbase = n0 + w * 16 + q4 * 4;
    float cn[4];
#pragma unroll
    for (int r = 0; r < 4; ++r) {
        int n = nbase + r;
        cn[r] = (n < NN) ? cq[bb * NN + n] : 0.f;
    }
    __syncthreads();

    // ---- epilogue phase 1: compute bf16 weights into registers ----
    u16x8 wvr[4];
#pragma unroll
    for (int r = 0; r < 4; ++r) {
        int nloc = w * 16 + q4 * 4 + r;
#pragma unroll
        for (int jt = 0; jt < 8; ++jt) {
            int j = j0 + jt * 16 + m16;
            float sv = sstg[nloc * 132 + jt * 16 + m16];
            float dg = (acc[jt][r] + cn[r]) * SCALE;
            float s  = 1.f / (1.f + __expf(-dg));
            float wv = (j < TN) ? s * sv * SCALE : 0.f;
            __bf16 wb16 = (__bf16)wv;
            wvr[r][jt] = *(unsigned short*)&wb16;
        }
    }
    __syncthreads();   // all sstg reads done -> safe to overlay

    // ---- phase 2: scatter u16 to LDS (2-way aliasing only = free) ----
    unsigned short* wb = (unsigned short*)sstg;   // stride 136
#pragma unroll
    for (int r = 0; r < 4; ++r) {
        int nloc = w * 16 + q4 * 4 + r;
#pragma unroll
        for (int jt = 0; jt < 8; ++jt)
            wb[nloc * 136 + jt * 16 + m16] = wvr[r][jt];
    }
    __syncthreads();

    // ---- phase 3: coalesced b128 stores ----
#pragma unroll
    for (int i = 0; i < 4; ++i) {
        int chunk = t + i * 256;          // 0..1023
        int row = chunk >> 4, c8 = (chunk & 15) * 8;
        int n = n0 + row;
        if (n < NN) {
            u16x8 v = *(const u16x8*)&wb[row * 136 + c8];
            *(u16x8*)((unsigned short*)sag + (size_t)(bb * NN + n) * SST1 + j0 + c8) = v;
        }
    }
}

// ---------------------------------------------------------------------------
// Softmax+topk, one wave per row, zero LDS (occupancy-unbound). Reads the
// score row, exact kk-th-largest threshold via ballot binary search, writes
// normalized bf16 weights IN PLACE back into sag. Replaces the softmax half
// of the old fused attn_k (which was pinned at 2 blocks/CU by 62 KB LDS).
// ---------------------------------------------------------------------------
__global__ __launch_bounds__(256) void smax_k(__bf16* __restrict__ sagB,
                                              const int* __restrict__ topk_p) {
    int t = threadIdx.x;
    int wid = t >> 6, lane = t & 63;
    int row = blockIdx.x * 4 + wid;
    if (row >= ROWSH) return;

    int topkv = *topk_p;
    bool selAll = (topkv <= 0);
    int kk = 0;
    if (!selAll) {
        kk = (topkv < 5) ? topkv * NN : topkv;
        if (kk > TN) kk = TN;
    }

    u16x8* src = (u16x8*)((unsigned short*)sagB + (size_t)row * SST1);
    u16x8 va[8];
#pragma unroll
    for (int ci = 0; ci < 8; ++ci) {
        int c = lane + (ci << 6);
        u16x8 v = {0, 0, 0, 0, 0, 0, 0, 0};
        if (c < 464) v = src[c];
        va[ci] = v;
    }
    // row max (values >= 0; bf16 bit order = value order; pads 0)
    int vmb = 0;
#pragma unroll
    for (int ci = 0; ci < 8; ++ci)
#pragma unroll
        for (int e = 0; e < 8; ++e) vmb = max(vmb, (int)va[ci][e]);
#pragma unroll
    for (int m = 32; m > 0; m >>= 1) vmb = max(vmb, __shfl_xor(vmb, m, 64));
    float vmax = __uint_as_float(((unsigned)vmb) << 16);

    // exact kk-th largest: smallest T with cnt(>T) < kk (ballot+popcount)
    unsigned thrb = 0;
    if (!selAll) {
        unsigned lo = 0, hi = (unsigned)vmb;
        while (lo < hi) {
            unsigned mid = (lo + hi) >> 1;
            int cnt = 0;
#pragma unroll
            for (int ci = 0; ci < 8; ++ci)
#pragma unroll
                for (int e = 0; e < 8; ++e)
                    cnt += (int)__popcll(__ballot((unsigned)va[ci][e] > mid));
            if (cnt < kk) hi = mid; else lo = mid + 1;
        }
        thrb = lo;
    }

    // softmax sum over selected (cache exp as bf16 in-place)
    float local = 0.f;
#pragma unroll
    for (int ci = 0; ci < 8; ++ci) {
        int c = lane + (ci << 6);
        int nvv = (c < 460) ? 8 : ((c == 460) ? 4 : 0);
#pragma unroll
        for (int e = 0; e < 8; ++e) {
            unsigned u = va[ci][e];
            bool sel = selAll ? (e < nvv) : (u > thrb);
            float ev = sel ? __expf(__uint_as_float(u << 16) - vmax) : 0.f;
            local += ev;
            __bf16 eb = (__bf16)ev;
            va[ci][e] = *(unsigned short*)&eb;
        }
    }
    local = wred_sum(local);
    bool uni = !(local > 0.f);
    float inv = uni ? 0.f : 1.f / local;
    float uval = 1.f / (float)TN;
#pragma unroll
    for (int ci = 0; ci < 8; ++ci) {
        int c = lane + (ci << 6);
        if (c < 464) {
            int nvv = (c < 460) ? 8 : ((c == 460) ? 4 : 0);
            bf16x8 o;
#pragma unroll
            for (int e = 0; e < 8; ++e) {
                if (uni) o[e] = (e < nvv) ? (__bf16)uval : (__bf16)0.f;
                else {
                    unsigned short us = va[ci][e];
                    float ev = (float)(*(__bf16*)&us);
                    o[e] = (__bf16)(ev * inv);
                }
            }
            *(bf16x8*)&src[c] = o;
        }
    }
}

// ---------------------------------------------------------------------------
// PV as a clean GEMM: h[b,n,d] = sag[b,n,:] @ xnT[b,d,:]^T + y32.
// Block = 16 rows x 64 d, 4 waves (one 16-wide d-tile each, full K=3712,
// dual accumulators). A-fragment fully populated (no m16<8 zero waste),
// no LDS, no reduce. Weight pads (j in [3684,3712)) are exact zeros.
// ---------------------------------------------------------------------------
__global__ __launch_bounds__(256) void pv_k(const __bf16* __restrict__ sagB,
                                            const __bf16* __restrict__ xnT,
                                            const float* __restrict__ y32,
                                            float* __restrict__ h) {
    int bb = blockIdx.y, n0 = blockIdx.x * 16;
    int wid = threadIdx.x >> 6, lane = threadIdx.x & 63;
    int m16 = lane & 15, q4 = lane >> 4;

    int arow = min(n0 + m16, NN - 1);   // clamp: garbage rows masked at store
    const __bf16* ab  = sagB + (size_t)(bb * NN + arow) * SST1 + q4 * 8;
    const __bf16* bbp = xnT + ((size_t)bb * 64 + wid * 16 + m16) * SSTR + q4 * 8;

    f32x4 acc0 = {0.f, 0.f, 0.f, 0.f}, acc1 = {0.f, 0.f, 0.f, 0.f};
#pragma unroll 4
    for (int ks = 0; ks < 116; ks += 2) {
        bf16x8 a0 = *(const bf16x8*)(ab + ks * 32);
        bf16x8 b0 = *(const bf16x8*)(bbp + ks * 32);
        bf16x8 a1 = *(const bf16x8*)(ab + ks * 32 + 32);
        bf16x8 b1 = *(const bf16x8*)(bbp + ks * 32 + 32);
        acc0 = __builtin_amdgcn_mfma_f32_16x16x32_bf16(a0, b0, acc0, 0, 0, 0);
        acc1 = __builtin_amdgcn_mfma_f32_16x16x32_bf16(a1, b1, acc1, 0, 0, 0);
    }
    // C layout: row = q4*4+r (A-row), col = m16 (B-row = d within tile)
#pragma unroll
    for (int r = 0; r < 4; ++r) {
        int n = n0 + q4 * 4 + r;
        if (n < NN) {
            size_t o = (size_t)(bb * NN + n) * 64 + wid * 16 + m16;
            h[o] = acc0[r] + acc1[r] + y32[o];
        }
    }
}

// ---------------------------------------------------------------------------
// FFN via MFMA bf16: LN -> zb16(LDS) -> @fc1^T+relu -> ab16(LDS)
// -> @fc2^T + h + b. 16 rows/block, LDS ~11 KB.
// ---------------------------------------------------------------------------
__global__ __launch_bounds__(256) void ffn_k(const float* __restrict__ h,
                                             const float* __restrict__ g,
                                             const float* __restrict__ bln,
                                             const __bf16* __restrict__ fc1b16,
                                             const float* __restrict__ fc1b,
                                             const __bf16* __restrict__ fc2b16,
                                             const float* __restrict__ fc2b,
                                             float* __restrict__ out) {
    __shared__ __bf16 zb[16 * 68];
    __shared__ __bf16 ab[16 * 264];
    int t = threadIdx.x, r0 = blockIdx.x * 16;
    int wid = t >> 6, lane = t & 63;
    int m16 = lane & 15, q4 = lane >> 4;

#pragma unroll
    for (int q = 0; q < 4; ++q) {
        int rl = wid * 4 + q;
        float val = h[(size_t)(r0 + rl) * 64 + lane];
        float mu  = wred_sum(val) * (1.f / 64.f);
        float dv  = val - mu;
        float var = wred_sum(dv * dv) * (1.f / 64.f);
        zb[rl * 68 + lane] = (__bf16)(dv * rsqrtf(var + 1e-5f) * g[lane] + bln[lane]);
    }
    __syncthreads();

    bf16x8 a0 = *(const bf16x8*)&zb[m16 * 68 + q4 * 8];
    bf16x8 a1 = *(const bf16x8*)&zb[m16 * 68 + 32 + q4 * 8];
#pragma unroll
    for (int jt2 = 0; jt2 < 4; ++jt2) {
        int j0t = (wid * 4 + jt2) * 16;
        const __bf16* bp = fc1b16 + (size_t)(j0t + m16) * 64 + q4 * 8;
        f32x4 c = {0.f, 0.f, 0.f, 0.f};
        c = __builtin_amdgcn_mfma_f32_16x16x32_bf16(a0, *(const bf16x8*)bp, c, 0, 0, 0);
        c = __builtin_amdgcn_mfma_f32_16x16x32_bf16(a1, *(const bf16x8*)(bp + 32), c, 0, 0, 0);
        int j = j0t + m16;
        float bias = fc1b[j];
#pragma unroll
        for (int r = 0; r < 4; ++r)
            ab[(q4 * 4 + r) * 264 + j] = (__bf16)fmaxf(c[r] + bias, 0.f);
    }
    __syncthreads();

    f32x4 c2a = {0.f, 0.f, 0.f, 0.f}, c2b = {0.f, 0.f, 0.f, 0.f};
    const __bf16* b2p = fc2b16 + (size_t)(wid * 16 + m16) * 256 + q4 * 8;
#pragma unroll
    for (int k8 = 0; k8 < 8; k8 += 2) {
        bf16x8 aa0 = *(const bf16x8*)&ab[m16 * 264 + k8 * 32 + q4 * 8];
        bf16x8 aa1 = *(const bf16x8*)&ab[m16 * 264 + (k8 + 1) * 32 + q4 * 8];
        c2a = __builtin_amdgcn_mfma_f32_16x16x32_bf16(aa0, *(const bf16x8*)(b2p + k8 * 32), c2a, 0, 0, 0);
        c2b = __builtin_amdgcn_mfma_f32_16x16x32_bf16(aa1, *(const bf16x8*)(b2p + (k8 + 1) * 32), c2b, 0, 0, 0);
    }
    int d = wid * 16 + m16;
    float bias2 = fc2b[d];
#pragma unroll
    for (int r = 0; r < 4; ++r) {
        size_t row = (size_t)(r0 + q4 * 4 + r);
        out[row * 64 + d] = h[row * 64 + d] + c2a[r] + c2b[r] + bias2;
    }
}

extern "C" void kernel_launch(void* const* d_in, const int* in_sizes, int n_in,
                              void* d_out, int out_size, void* d_ws, size_t ws_size,
                              hipStream_t stream) {
    const float* x    = (const float*)d_in[0];
    const float* stg  = (const float*)d_in[1];
    const int*   topk = (const int*)d_in[2];
    const float* qw   = (const float*)d_in[3];
    const float* qb   = (const float*)d_in[4];
    const float* kw   = (const float*)d_in[5];
    const float* kb   = (const float*)d_in[6];
    const float* lng  = (const float*)d_in[7];
    const float* lnb  = (const float*)d_in[8];
    const float* flng = (const float*)d_in[9];
    const float* flnb = (const float*)d_in[10];
    const float* fc1w = (const float*)d_in[11];
    const float* fc1b = (const float*)d_in[12];
    const float* fc2w = (const float*)d_in[13];
    const float* fc2b = (const float*)d_in[14];
    float* out = (float*)d_out;

    float* ws = (float*)d_ws;
    __bf16* xnb = (__bf16*)ws;                 // ROWSX*64 bf16 = 1,886,208 f
    float* p1   = ws + 1886208;
    __bf16* xnT = (__bf16*)p1;                 // 16*64*3840 bf16 = 1,966,080 f
    float* p2   = p1 + 1966080;
    __bf16* qtb = (__bf16*)p2;                 // 4928*64 bf16 = 157,696 f
    float* y32  = p2 + 157696;                 // 314,368 f
    float* cq   = y32 + 314368;                // 4,928 f
    float* M    = cq + 4928;                   // 4,096
    float* b2   = M + 4096;                    // 64
    float* vv   = b2 + 64;                     // 64
    float* cc   = vv + 64;                     // 16
    __bf16* fc1b16 = (__bf16*)(cc + 16);       // 8,192 f
    __bf16* fc2b16 = (__bf16*)((float*)fc1b16 + 8192);  // 8,192 f
    __bf16* sag = (__bf16*)((float*)fc2b16 + 8192);     // ROWSH*3712 bf16 = 9,116,672 f
    float* h    = (float*)sag + 9116672;       // 314,368 f

    fold_k<<<64, 64, 0, stream>>>(qw, qb, kw, kb, M, b2, vv, cc);
    wconv_k<<<128, 256, 0, stream>>>(fc1w, fc2w, fc1b16, fc2b16);
    ln_k<<<(ROWSX + 3) / 4, 256, 0, stream>>>(x, lng, lnb, xnb, y32);
    t_k<<<dim3((TN + 63) / 64, BB), 256, 0, stream>>>(xnb, xnT);
    qt_k<<<(ROWSH + 3) / 4, 256, 0, stream>>>(y32, M, b2, vv, cc, qtb, cq);
    score_k<<<dim3((TN + 127) / 128, (NN + 63) / 64, BB), 256, 0, stream>>>(qtb, cq, xnb, stg, sag);
    smax_k<<<(ROWSH + 3) / 4, 256, 0, stream>>>(sag, topk);
    pv_k<<<dim3((NN + 15) / 16, BB), 256, 0, stream>>>(sag, xnT, y32, h);
    ffn_k<<<ROWSH / 16, 256, 0, stream>>>(h, flng, flnb, fc1b16, fc1b, fc2b16, fc2b, out);
}

// Round 2
// 268.966 us; speedup vs baseline: 1.0870x; 1.0870x over previous
//
#include <hip/hip_runtime.h>

typedef __bf16 bf16x8 __attribute__((ext_vector_type(8)));
typedef float  f32x4  __attribute__((ext_vector_type(4)));
typedef unsigned short u16x8 __attribute__((ext_vector_type(8)));

// Problem constants
constexpr int BB    = 16;
constexpr int TT    = 12;
constexpr int NN    = 307;
constexpr int TN    = TT * NN;        // 3684
constexpr int ROWSX = BB * TT * NN;   // 58944
constexpr int ROWSH = BB * NN;        // 4912
constexpr int SST1  = 3712;           // sag row stride (464 x b128 chunks)
constexpr int SSTR  = 3840;           // xnT row stride
constexpr int HPS   = ROWSH * 64;     // hp slab stride (314368 floats)
constexpr int KQ    = 928;            // pv K-split chunk (3712/4)
constexpr float SCALE = 0.125f;

__device__ __forceinline__ float wred_sum(float v) {
#pragma unroll
    for (int m = 32; m > 0; m >>= 1) v += __shfl_xor(v, m, 64);
    return v;
}

// ---------------------------------------------------------------------------
// Fold q/k projections: dg = q.k = qt.x_ + c
// ---------------------------------------------------------------------------
__global__ void fold_k(const float* __restrict__ qw, const float* __restrict__ qb,
                       const float* __restrict__ kw, const float* __restrict__ kb,
                       float* __restrict__ M, float* __restrict__ b2,
                       float* __restrict__ vv, float* __restrict__ cc) {
    int e = blockIdx.x, d = threadIdx.x;
    float acc = 0.f;
    for (int dp = 0; dp < 64; ++dp) acc += qw[dp * 64 + e] * kw[dp * 64 + d];
    M[e * 64 + d] = acc;
    float vp = wred_sum(qw[d * 64 + e] * kb[d]);
    if (d == 0) vv[e] = vp;
    if (e == 0) {
        float b = 0.f;
        for (int dp = 0; dp < 64; ++dp) b += qb[dp] * kw[dp * 64 + d];
        b2[d] = b;
        float cp = wred_sum(qb[d] * kb[d]);
        if (d == 0) *cc = cp;
    }
}

// ---------------------------------------------------------------------------
// fc1w/fc2w fp32 -> bf16
// ---------------------------------------------------------------------------
__global__ void wconv_k(const float* __restrict__ fc1w, const float* __restrict__ fc2w,
                        __bf16* __restrict__ fc1b16, __bf16* __restrict__ fc2b16) {
    int i = blockIdx.x * 256 + threadIdx.x;
    if (i < 16384) fc1b16[i] = (__bf16)fc1w[i];
    else fc2b16[i - 16384] = (__bf16)fc2w[i - 16384];
}

// ---------------------------------------------------------------------------
// LayerNorm -> xnb (bf16) + y32 (fp32, t==11 slab)
// ---------------------------------------------------------------------------
__global__ __launch_bounds__(256) void ln_k(const float* __restrict__ x,
                                            const float* __restrict__ g,
                                            const float* __restrict__ b,
                                            __bf16* __restrict__ xnb,
                                            float* __restrict__ y32) {
    int w = threadIdx.x >> 6, l = threadIdx.x & 63;
    int r = blockIdx.x * 4 + w;
    if (r >= ROWSX) return;
    float val = x[r * 64 + l];
    float mu  = wred_sum(val) * (1.f / 64.f);
    float dv  = val - mu;
    float var = wred_sum(dv * dv) * (1.f / 64.f);
    float xv  = dv * rsqrtf(var + 1e-5f) * g[l] + b[l];
    xnb[(size_t)r * 64 + l] = (__bf16)xv;
    int t = (r / NN) % TT;
    if (t == TT - 1) {
        int bbv = r / (NN * TT), n = r % NN;
        y32[(bbv * NN + n) * 64 + l] = xv;
    }
}

// ---------------------------------------------------------------------------
// Transpose xnb[b,j,d] -> xnT[b,d,j] (stride SSTR; j>=TN zero within tiles)
// ---------------------------------------------------------------------------
__global__ __launch_bounds__(256) void t_k(const __bf16* __restrict__ xnb,
                                           __bf16* __restrict__ xnT) {
    __shared__ unsigned short tile[64][65];
    int bb = blockIdx.y, j0 = blockIdx.x * 64, t = threadIdx.x;
    const unsigned short* src = (const unsigned short*)xnb;
    unsigned short* dst = (unsigned short*)xnT;
#pragma unroll
    for (int i = 0; i < 16; ++i) {
        int f = t + 256 * i, jr = f >> 6, dc = f & 63;
        int j = j0 + jr;
        tile[jr][dc] = (j < TN) ? src[((size_t)bb * TN + j) * 64 + dc] : (unsigned short)0;
    }
    __syncthreads();
#pragma unroll
    for (int i = 0; i < 16; ++i) {
        int f = t + 256 * i, d = f >> 6, jj = f & 63;
        dst[((size_t)bb * 64 + d) * SSTR + j0 + jj] = tile[jj][d];
    }
}

// ---------------------------------------------------------------------------
// qt[row] = y_ @ M + b2 (bf16);  cq[row] = y_.v + cc
// ---------------------------------------------------------------------------
__global__ __launch_bounds__(256) void qt_k(const float* __restrict__ y32,
                                            const float* __restrict__ M,
                                            const float* __restrict__ b2,
                                            const float* __restrict__ vv,
                                            const float* __restrict__ ccp,
                                            __bf16* __restrict__ qtb,
                                            float* __restrict__ cq) {
    int w = threadIdx.x >> 6, l = threadIdx.x & 63;
    int rr = blockIdx.x * 4 + w;
    if (rr >= ROWSH) return;
    float y = y32[rr * 64 + l];
    float acc = b2[l];
#pragma unroll
    for (int e = 0; e < 64; ++e) acc += __shfl(y, e, 64) * M[e * 64 + l];
    qtb[(size_t)rr * 64 + l] = (__bf16)acc;
    float cp = wred_sum(y * vv[l]);
    if (l == 0) cq[rr] = cp + *ccp;
}

// ---------------------------------------------------------------------------
// Score GEMM via MFMA. v2: NO stg LDS staging (stg read once per element ->
// staging bought zero reuse, cost 33.8KB LDS and a barrier; now read direct
// in epilogue, 4x64B segments/instr, full line utilization). LDS is only the
// 17.4KB u16 transpose buffer -> 6-8 blocks/CU (was 4). Single barrier.
// ---------------------------------------------------------------------------
__global__ __launch_bounds__(256) void score_k(const __bf16* __restrict__ qtb,
                                               const float* __restrict__ cq,
                                               const __bf16* __restrict__ xnb,
                                               const float* __restrict__ stg,
                                               __bf16* __restrict__ sag) {
    __shared__ unsigned short wb[64 * 136];   // 17.4 KB
    int bb = blockIdx.z, n0 = blockIdx.y * 64, j0 = blockIdx.x * 128;
    int t = threadIdx.x;
    int w = t >> 6, lane = t & 63;
    int m16 = lane & 15, q4 = lane >> 4;

    // ---- MFMA: 64n x 128j, K=64 ----
    const bf16x8* ap = (const bf16x8*)(qtb + ((size_t)bb * NN + n0 + w * 16 + m16) * 64);
    bf16x8 a0 = ap[q4], a1 = ap[q4 + 4];
    f32x4 acc[8];
#pragma unroll
    for (int jt = 0; jt < 8; ++jt) {
        const bf16x8* bp = (const bf16x8*)(xnb + ((size_t)bb * TN + j0 + jt * 16 + m16) * 64);
        bf16x8 b0 = bp[q4], b1 = bp[q4 + 4];
        f32x4 c = {0.f, 0.f, 0.f, 0.f};
        c = __builtin_amdgcn_mfma_f32_16x16x32_bf16(a0, b0, c, 0, 0, 0);
        c = __builtin_amdgcn_mfma_f32_16x16x32_bf16(a1, b1, c, 0, 0, 0);
        acc[jt] = c;
    }
    int nbase = n0 + w * 16 + q4 * 4;
    float cn[4];
#pragma unroll
    for (int r = 0; r < 4; ++r) {
        int n = nbase + r;
        cn[r] = (n < NN) ? cq[bb * NN + n] : 0.f;
    }

    // ---- epilogue: sigmoid(dg)*stg*scale, stg read direct from global ----
    const float* stgb = stg + (size_t)bb * NN * TN;
#pragma unroll
    for (int r = 0; r < 4; ++r) {
        int nloc = w * 16 + q4 * 4 + r;
        const float* srow = stgb + (size_t)min(nbase + r, NN - 1) * TN;
        u16x8 wvr;
#pragma unroll
        for (int jt = 0; jt < 8; ++jt) {
            int j = j0 + jt * 16 + m16;
            float sv = (j < TN) ? srow[j] : 0.f;
            float dg = (acc[jt][r] + cn[r]) * SCALE;
            float s  = 1.f / (1.f + __expf(-dg));
            float wv = (j < TN) ? s * sv * SCALE : 0.f;
            __bf16 wb16 = (__bf16)wv;
            wvr[jt] = *(unsigned short*)&wb16;
        }
        // scatter u16 to LDS (2-way aliasing only = free)
#pragma unroll
        for (int jt = 0; jt < 8; ++jt)
            wb[nloc * 136 + jt * 16 + m16] = wvr[jt];
    }
    __syncthreads();

    // ---- coalesced b128 stores ----
#pragma unroll
    for (int i = 0; i < 4; ++i) {
        int chunk = t + i * 256;          // 0..1023
        int row = chunk >> 4, c8 = (chunk & 15) * 8;
        int n = n0 + row;
        if (n < NN) {
            u16x8 v = *(const u16x8*)&wb[row * 136 + c8];
            *(u16x8*)((unsigned short*)sag + (size_t)(bb * NN + n) * SST1 + j0 + c8) = v;
        }
    }
}

// ---------------------------------------------------------------------------
// Softmax+topk, one wave per row, zero LDS. v2: writes UNnormalized exp
// weights in place + per-row sum to rsum[]; pv_k applies 1/rsum in its
// epilogue. Deletes the whole renormalize pass (~190 VALU ops/lane).
// ---------------------------------------------------------------------------
__global__ __launch_bounds__(256) void smax_k(__bf16* __restrict__ sagB,
                                              const int* __restrict__ topk_p,
                                              float* __restrict__ rsum) {
    int t = threadIdx.x;
    int wid = t >> 6, lane = t & 63;
    int row = blockIdx.x * 4 + wid;
    if (row >= ROWSH) return;

    int topkv = *topk_p;
    bool selAll = (topkv <= 0);
    int kk = 0;
    if (!selAll) {
        kk = (topkv < 5) ? topkv * NN : topkv;
        if (kk > TN) kk = TN;
    }

    u16x8* src = (u16x8*)((unsigned short*)sagB + (size_t)row * SST1);
    u16x8 va[8];
#pragma unroll
    for (int ci = 0; ci < 8; ++ci) {
        int c = lane + (ci << 6);
        u16x8 v = {0, 0, 0, 0, 0, 0, 0, 0};
        if (c < 464) v = src[c];
        va[ci] = v;
    }
    // row max (values >= 0; bf16 bit order = value order; pads 0)
    int vmb = 0;
#pragma unroll
    for (int ci = 0; ci < 8; ++ci)
#pragma unroll
        for (int e = 0; e < 8; ++e) vmb = max(vmb, (int)va[ci][e]);
#pragma unroll
    for (int m = 32; m > 0; m >>= 1) vmb = max(vmb, __shfl_xor(vmb, m, 64));
    float vmax = __uint_as_float(((unsigned)vmb) << 16);

    // exact kk-th largest: smallest T with cnt(>T) < kk (ballot+popcount)
    unsigned thrb = 0;
    if (!selAll) {
        unsigned lo = 0, hi = (unsigned)vmb;
        while (lo < hi) {
            unsigned mid = (lo + hi) >> 1;
            int cnt = 0;
#pragma unroll
            for (int ci = 0; ci < 8; ++ci)
#pragma unroll
                for (int e = 0; e < 8; ++e)
                    cnt += (int)__popcll(__ballot((unsigned)va[ci][e] > mid));
            if (cnt < kk) hi = mid; else lo = mid + 1;
        }
        thrb = lo;
    }

    // exp over selected (store unnormalized exp as bf16)
    float local = 0.f;
#pragma unroll
    for (int ci = 0; ci < 8; ++ci) {
        int c = lane + (ci << 6);
        int nvv = (c < 460) ? 8 : ((c == 460) ? 4 : 0);
#pragma unroll
        for (int e = 0; e < 8; ++e) {
            unsigned u = va[ci][e];
            bool sel = selAll ? (e < nvv) : (u > thrb);
            float ev = sel ? __expf(__uint_as_float(u << 16) - vmax) : 0.f;
            local += ev;
            __bf16 eb = (__bf16)ev;
            va[ci][e] = *(unsigned short*)&eb;
        }
    }
    local = wred_sum(local);
    bool uni = !(local > 0.f);
    if (lane == 0) rsum[row] = uni ? (float)TN : local;

    if (uni) {
        // degenerate: uniform weight 1.0 on valid cols, rsum=TN
        __bf16 one = (__bf16)1.f, zero = (__bf16)0.f;
#pragma unroll
        for (int ci = 0; ci < 8; ++ci) {
            int c = lane + (ci << 6);
            if (c < 464) {
                int nvv = (c < 460) ? 8 : ((c == 460) ? 4 : 0);
                bf16x8 o;
#pragma unroll
                for (int e = 0; e < 8; ++e) o[e] = (e < nvv) ? one : zero;
                *(bf16x8*)&src[c] = o;
            }
        }
    } else {
#pragma unroll
        for (int ci = 0; ci < 8; ++ci) {
            int c = lane + (ci << 6);
            if (c < 464) src[c] = va[ci];
        }
    }
}

// ---------------------------------------------------------------------------
// PV GEMM, K-split 4 across blocks: hp[kq][b,n,d] = (sag[b,n,kq-chunk] @
// xnT[b,d,kq-chunk]^T) / rsum[b,n]  (+ y32 on kq==0). Grid 20x4x16 = 1280
// blocks -> ~5 blocks/CU (was 320 -> 1.25). ffn_k sums the 4 slabs.
// ---------------------------------------------------------------------------
__global__ __launch_bounds__(256) void pv_k(const __bf16* __restrict__ sagB,
                                            const __bf16* __restrict__ xnT,
                                            const float* __restrict__ y32,
                                            const float* __restrict__ rsum,
                                            float* __restrict__ hp) {
    int bb = blockIdx.z, kq = blockIdx.y, n0 = blockIdx.x * 16;
    int wid = threadIdx.x >> 6, lane = threadIdx.x & 63;
    int m16 = lane & 15, q4 = lane >> 4;

    int arow = min(n0 + m16, NN - 1);   // clamp: garbage rows masked at store
    const __bf16* ab  = sagB + (size_t)(bb * NN + arow) * SST1 + kq * KQ + q4 * 8;
    const __bf16* bbp = xnT + ((size_t)bb * 64 + wid * 16 + m16) * SSTR + kq * KQ + q4 * 8;

    f32x4 acc0 = {0.f, 0.f, 0.f, 0.f}, acc1 = {0.f, 0.f, 0.f, 0.f};
#pragma unroll 4
    for (int ks = 0; ks < 29; ++ks) {               // 29 * K32 = 928
        bf16x8 a = *(const bf16x8*)(ab + ks * 32);
        bf16x8 b = *(const bf16x8*)(bbp + ks * 32);
        if (ks & 1) acc1 = __builtin_amdgcn_mfma_f32_16x16x32_bf16(a, b, acc1, 0, 0, 0);
        else        acc0 = __builtin_amdgcn_mfma_f32_16x16x32_bf16(a, b, acc0, 0, 0, 0);
    }
    // C layout: row = q4*4+r (A-row = n), col = m16 (B-row = d within tile)
#pragma unroll
    for (int r = 0; r < 4; ++r) {
        int n = n0 + q4 * 4 + r;
        if (n < NN) {
            size_t o = (size_t)(bb * NN + n) * 64 + wid * 16 + m16;
            float inv = 1.f / rsum[bb * NN + n];
            float v = (acc0[r] + acc1[r]) * inv;
            if (kq == 0) v += y32[o];
            hp[(size_t)kq * HPS + o] = v;
        }
    }
}

// ---------------------------------------------------------------------------
// FFN via MFMA bf16: h = sum(hp[0..3]) -> LN -> @fc1^T+relu -> @fc2^T + h + b.
// ---------------------------------------------------------------------------
__global__ __launch_bounds__(256) void ffn_k(const float* __restrict__ hp,
                                             const float* __restrict__ g,
                                             const float* __restrict__ bln,
                                             const __bf16* __restrict__ fc1b16,
                                             const float* __restrict__ fc1b,
                                             const __bf16* __restrict__ fc2b16,
                                             const float* __restrict__ fc2b,
                                             float* __restrict__ out) {
    __shared__ __bf16 zb[16 * 68];
    __shared__ __bf16 ab[16 * 264];
    int t = threadIdx.x, r0 = blockIdx.x * 16;
    int wid = t >> 6, lane = t & 63;
    int m16 = lane & 15, q4 = lane >> 4;

#pragma unroll
    for (int q = 0; q < 4; ++q) {
        int rl = wid * 4 + q;
        size_t i = (size_t)(r0 + rl) * 64 + lane;
        float val = hp[i] + hp[HPS + i] + hp[2 * HPS + i] + hp[3 * HPS + i];
        float mu  = wred_sum(val) * (1.f / 64.f);
        float dv  = val - mu;
        float var = wred_sum(dv * dv) * (1.f / 64.f);
        zb[rl * 68 + lane] = (__bf16)(dv * rsqrtf(var + 1e-5f) * g[lane] + bln[lane]);
    }
    __syncthreads();

    bf16x8 a0 = *(const bf16x8*)&zb[m16 * 68 + q4 * 8];
    bf16x8 a1 = *(const bf16x8*)&zb[m16 * 68 + 32 + q4 * 8];
#pragma unroll
    for (int jt2 = 0; jt2 < 4; ++jt2) {
        int j0t = (wid * 4 + jt2) * 16;
        const __bf16* bp = fc1b16 + (size_t)(j0t + m16) * 64 + q4 * 8;
        f32x4 c = {0.f, 0.f, 0.f, 0.f};
        c = __builtin_amdgcn_mfma_f32_16x16x32_bf16(a0, *(const bf16x8*)bp, c, 0, 0, 0);
        c = __builtin_amdgcn_mfma_f32_16x16x32_bf16(a1, *(const bf16x8*)(bp + 32), c, 0, 0, 0);
        int j = j0t + m16;
        float bias = fc1b[j];
#pragma unroll
        for (int r = 0; r < 4; ++r)
            ab[(q4 * 4 + r) * 264 + j] = (__bf16)fmaxf(c[r] + bias, 0.f);
    }
    __syncthreads();

    f32x4 c2a = {0.f, 0.f, 0.f, 0.f}, c2b = {0.f, 0.f, 0.f, 0.f};
    const __bf16* b2p = fc2b16 + (size_t)(wid * 16 + m16) * 256 + q4 * 8;
#pragma unroll
    for (int k8 = 0; k8 < 8; k8 += 2) {
        bf16x8 aa0 = *(const bf16x8*)&ab[m16 * 264 + k8 * 32 + q4 * 8];
        bf16x8 aa1 = *(const bf16x8*)&ab[m16 * 264 + (k8 + 1) * 32 + q4 * 8];
        c2a = __builtin_amdgcn_mfma_f32_16x16x32_bf16(aa0, *(const bf16x8*)(b2p + k8 * 32), c2a, 0, 0, 0);
        c2b = __builtin_amdgcn_mfma_f32_16x16x32_bf16(aa1, *(const bf16x8*)(b2p + (k8 + 1) * 32), c2b, 0, 0, 0);
    }
    int d = wid * 16 + m16;
    float bias2 = fc2b[d];
#pragma unroll
    for (int r = 0; r < 4; ++r) {
        size_t row = (size_t)(r0 + q4 * 4 + r);
        size_t o = row * 64 + d;
        float hsum = hp[o] + hp[HPS + o] + hp[2 * HPS + o] + hp[3 * HPS + o];
        out[o] = hsum + c2a[r] + c2b[r] + bias2;
    }
}

extern "C" void kernel_launch(void* const* d_in, const int* in_sizes, int n_in,
                              void* d_out, int out_size, void* d_ws, size_t ws_size,
                              hipStream_t stream) {
    const float* x    = (const float*)d_in[0];
    const float* stg  = (const float*)d_in[1];
    const int*   topk = (const int*)d_in[2];
    const float* qw   = (const float*)d_in[3];
    const float* qb   = (const float*)d_in[4];
    const float* kw   = (const float*)d_in[5];
    const float* kb   = (const float*)d_in[6];
    const float* lng  = (const float*)d_in[7];
    const float* lnb  = (const float*)d_in[8];
    const float* flng = (const float*)d_in[9];
    const float* flnb = (const float*)d_in[10];
    const float* fc1w = (const float*)d_in[11];
    const float* fc1b = (const float*)d_in[12];
    const float* fc2w = (const float*)d_in[13];
    const float* fc2b = (const float*)d_in[14];
    float* out = (float*)d_out;

    float* ws = (float*)d_ws;
    __bf16* xnb = (__bf16*)ws;                 // ROWSX*64 bf16 = 1,886,208 f
    float* p1   = ws + 1886208;
    __bf16* xnT = (__bf16*)p1;                 // 16*64*3840 bf16 = 1,966,080 f
    float* p2   = p1 + 1966080;
    __bf16* qtb = (__bf16*)p2;                 // 4928*64 bf16 = 157,696 f
    float* y32  = p2 + 157696;                 // 314,368 f
    float* cq   = y32 + 314368;                // 4,928 f
    float* M    = cq + 4928;                   // 4,096
    float* b2   = M + 4096;                    // 64
    float* vv   = b2 + 64;                     // 64
    float* cc   = vv + 64;                     // 16
    __bf16* fc1b16 = (__bf16*)(cc + 16);       // 8,192 f
    __bf16* fc2b16 = (__bf16*)((float*)fc1b16 + 8192);  // 8,192 f
    __bf16* sag = (__bf16*)((float*)fc2b16 + 8192);     // ROWSH*3712 bf16 = 9,116,672 f
    float* hp   = (float*)sag + 9116672;       // 4*314,368 f (K-split partials)
    float* rsum = hp + 4 * HPS;                // 4,928 f

    fold_k<<<64, 64, 0, stream>>>(qw, qb, kw, kb, M, b2, vv, cc);
    wconv_k<<<128, 256, 0, stream>>>(fc1w, fc2w, fc1b16, fc2b16);
    ln_k<<<(ROWSX + 3) / 4, 256, 0, stream>>>(x, lng, lnb, xnb, y32);
    t_k<<<dim3((TN + 63) / 64, BB), 256, 0, stream>>>(xnb, xnT);
    qt_k<<<(ROWSH + 3) / 4, 256, 0, stream>>>(y32, M, b2, vv, cc, qtb, cq);
    score_k<<<dim3((TN + 127) / 128, (NN + 63) / 64, BB), 256, 0, stream>>>(qtb, cq, xnb, stg, sag);
    smax_k<<<(ROWSH + 3) / 4, 256, 0, stream>>>(sag, topk, rsum);
    pv_k<<<dim3((NN + 15) / 16, 4, BB), 256, 0, stream>>>(sag, xnT, y32, rsum, hp);
    ffn_k<<<ROWSH / 16, 256, 0, stream>>>(hp, flng, flnb, fc1b16, fc1b, fc2b16, fc2b, out);
}

// Round 3
// 266.377 us; speedup vs baseline: 1.0976x; 1.0097x over previous
//
#include <hip/hip_runtime.h>

typedef __bf16 bf16x8 __attribute__((ext_vector_type(8)));
typedef float  f32x4  __attribute__((ext_vector_type(4)));
typedef unsigned short u16x8 __attribute__((ext_vector_type(8)));
typedef unsigned short u16x4 __attribute__((ext_vector_type(4)));

// Problem constants
constexpr int BB    = 16;
constexpr int TT    = 12;
constexpr int NN    = 307;
constexpr int TN    = TT * NN;        // 3684
constexpr int ROWSX = BB * TT * NN;   // 58944
constexpr int ROWSH = BB * NN;        // 4912
constexpr int SST1  = 3712;           // sag row stride (464 x b128 chunks)
constexpr int SSTR  = 3840;           // xnT row stride
constexpr int HPS   = ROWSH * 64;     // hp slab stride (314368 floats)
constexpr int KQ    = 928;            // pv K-split chunk (3712/4)
constexpr float SCALE = 0.125f;

__device__ __forceinline__ float wred_sum(float v) {
#pragma unroll
    for (int m = 32; m > 0; m >>= 1) v += __shfl_xor(v, m, 64);
    return v;
}

// ---------------------------------------------------------------------------
// Fold q/k projections: dg = q.k = qt.x_ + c
// ---------------------------------------------------------------------------
__global__ void fold_k(const float* __restrict__ qw, const float* __restrict__ qb,
                       const float* __restrict__ kw, const float* __restrict__ kb,
                       float* __restrict__ M, float* __restrict__ b2,
                       float* __restrict__ vv, float* __restrict__ cc) {
    int e = blockIdx.x, d = threadIdx.x;
    float acc = 0.f;
    for (int dp = 0; dp < 64; ++dp) acc += qw[dp * 64 + e] * kw[dp * 64 + d];
    M[e * 64 + d] = acc;
    float vp = wred_sum(qw[d * 64 + e] * kb[d]);
    if (d == 0) vv[e] = vp;
    if (e == 0) {
        float b = 0.f;
        for (int dp = 0; dp < 64; ++dp) b += qb[dp] * kw[dp * 64 + d];
        b2[d] = b;
        float cp = wred_sum(qb[d] * kb[d]);
        if (d == 0) *cc = cp;
    }
}

// ---------------------------------------------------------------------------
// fc1w/fc2w fp32 -> bf16
// ---------------------------------------------------------------------------
__global__ void wconv_k(const float* __restrict__ fc1w, const float* __restrict__ fc2w,
                        __bf16* __restrict__ fc1b16, __bf16* __restrict__ fc2b16) {
    int i = blockIdx.x * 256 + threadIdx.x;
    if (i < 16384) fc1b16[i] = (__bf16)fc1w[i];
    else fc2b16[i - 16384] = (__bf16)fc2w[i - 16384];
}

// ---------------------------------------------------------------------------
// Fused LayerNorm + transpose: x -> xnb[b,j,d] (bf16), xnT[b,d,j] (bf16,
// stride SSTR, zero pads), y32 (fp32, t==11 slab). A d=64 row fits inside a
// 64j-tile, so LN happens in-tile; deletes the separate ln_k pass (and its
// 7.5MB xnb re-read).
// ---------------------------------------------------------------------------
__global__ __launch_bounds__(256) void lnt_k(const float* __restrict__ x,
                                             const float* __restrict__ g,
                                             const float* __restrict__ b,
                                             __bf16* __restrict__ xnb,
                                             __bf16* __restrict__ xnT,
                                             float* __restrict__ y32) {
    __shared__ unsigned short tile[64][65];
    int bb = blockIdx.y, j0 = blockIdx.x * 64, t = threadIdx.x;
    int w = t >> 6, lane = t & 63;
    float gg = g[lane], bbv = b[lane];
    unsigned short* dst = (unsigned short*)xnT;
#pragma unroll 4
    for (int i = 0; i < 16; ++i) {
        int jr = w * 16 + i;
        int j = j0 + jr;
        bool valid = (j < TN);
        float val = valid ? x[((size_t)bb * TN + j) * 64 + lane] : 0.f;
        float mu  = wred_sum(val) * (1.f / 64.f);
        float dv  = val - mu;
        float var = wred_sum(dv * dv) * (1.f / 64.f);
        float xv  = dv * rsqrtf(var + 1e-5f) * gg + bbv;
        if (valid) {
            __bf16 xb = (__bf16)xv;
            xnb[((size_t)bb * TN + j) * 64 + lane] = xb;
            tile[jr][lane] = *(unsigned short*)&xb;
            if (j >= 11 * NN) y32[((size_t)bb * NN + (j - 11 * NN)) * 64 + lane] = xv;
        } else {
            tile[jr][lane] = 0;
        }
    }
    __syncthreads();
#pragma unroll
    for (int i = 0; i < 16; ++i) {
        int f = t + 256 * i, d = f >> 6, jj = f & 63;
        dst[((size_t)bb * 64 + d) * SSTR + j0 + jj] = tile[jj][d];
    }
}

// ---------------------------------------------------------------------------
// qt[row] = y_ @ M + b2 (bf16);  cq[row] = y_.v + cc
// ---------------------------------------------------------------------------
__global__ __launch_bounds__(256) void qt_k(const float* __restrict__ y32,
                                            const float* __restrict__ M,
                                            const float* __restrict__ b2,
                                            const float* __restrict__ vv,
                                            const float* __restrict__ ccp,
                                            __bf16* __restrict__ qtb,
                                            float* __restrict__ cq) {
    int w = threadIdx.x >> 6, l = threadIdx.x & 63;
    int rr = blockIdx.x * 4 + w;
    if (rr >= ROWSH) return;
    float y = y32[rr * 64 + l];
    float acc = b2[l];
#pragma unroll
    for (int e = 0; e < 64; ++e) acc += __shfl(y, e, 64) * M[e * 64 + l];
    qtb[(size_t)rr * 64 + l] = (__bf16)acc;
    float cp = wred_sum(y * vv[l]);
    if (l == 0) cq[rr] = cp + *ccp;
}

// ---------------------------------------------------------------------------
// Score GEMM via MFMA. v3: SWAPPED operands (A=xnb j-tile, B=qtb n-tile) so
// C maps row=j, col=n => each lane's 4 acc regs are 4 CONSECUTIVE j at fixed
// n. stg epilogue read becomes one aligned float4 per (jt,nt): 8 dwordx4 per
// thread instead of 32 scattered dwords. LDS transpose writes become b64.
// ---------------------------------------------------------------------------
__global__ __launch_bounds__(256) void score_k(const __bf16* __restrict__ qtb,
                                               const float* __restrict__ cq,
                                               const __bf16* __restrict__ xnb,
                                               const float* __restrict__ stg,
                                               __bf16* __restrict__ sag) {
    __shared__ unsigned short wb[64 * 144];   // 18.4 KB  [n(64)][j(128+pad)]
    int bb = blockIdx.z, n0 = blockIdx.y * 64, j0 = blockIdx.x * 128;
    int t = threadIdx.x;
    int w = t >> 6, lane = t & 63;
    int m16 = lane & 15, q4 = lane >> 4;

    // ---- A fragments: xnb rows j (2 jt tiles per wave) ----
    bf16x8 a[2][2];
#pragma unroll
    for (int jj = 0; jj < 2; ++jj) {
        const bf16x8* ap = (const bf16x8*)(xnb + ((size_t)bb * TN + j0 + (w * 2 + jj) * 16 + m16) * 64);
        a[jj][0] = ap[q4];
        a[jj][1] = ap[q4 + 4];
    }

    // ---- MFMA: C[j_local][n_local], 2 jt x 4 nt tiles per wave ----
    f32x4 acc[2][4];
#pragma unroll
    for (int nt = 0; nt < 4; ++nt) {
        const bf16x8* bp = (const bf16x8*)(qtb + ((size_t)bb * NN + n0 + nt * 16 + m16) * 64);
        bf16x8 b0 = bp[q4], b1 = bp[q4 + 4];
#pragma unroll
        for (int jj = 0; jj < 2; ++jj) {
            f32x4 c = {0.f, 0.f, 0.f, 0.f};
            c = __builtin_amdgcn_mfma_f32_16x16x32_bf16(a[jj][0], b0, c, 0, 0, 0);
            c = __builtin_amdgcn_mfma_f32_16x16x32_bf16(a[jj][1], b1, c, 0, 0, 0);
            acc[jj][nt] = c;
        }
    }

    // ---- epilogue: sigmoid(dg)*stg*scale; stg via aligned float4 ----
    const float* stgb = stg + (size_t)bb * NN * TN;
#pragma unroll
    for (int nt = 0; nt < 4; ++nt) {
        int n = n0 + nt * 16 + m16;
        float cnv = (n < NN) ? cq[bb * NN + n] : 0.f;
        const float* srow = stgb + (size_t)min(n, NN - 1) * TN;
#pragma unroll
        for (int jj = 0; jj < 2; ++jj) {
            int jb = j0 + (w * 2 + jj) * 16 + q4 * 4;   // 4-aligned; TN is 4-aligned
            float4 sv = {0.f, 0.f, 0.f, 0.f};
            if (jb < TN) sv = *(const float4*)(srow + jb);
            u16x4 hw;
            float svv[4] = {sv.x, sv.y, sv.z, sv.w};
#pragma unroll
            for (int r = 0; r < 4; ++r) {
                float dg = (acc[jj][nt][r] + cnv) * SCALE;
                float s  = 1.f / (1.f + __expf(-dg));
                float wv = (jb + r < TN) ? s * svv[r] * SCALE : 0.f;
                __bf16 wb16 = (__bf16)wv;
                hw[r] = *(unsigned short*)&wb16;
            }
            *(u16x4*)&wb[(nt * 16 + m16) * 144 + (w * 2 + jj) * 16 + q4 * 4] = hw;
        }
    }
    __syncthreads();

    // ---- coalesced b128 stores ----
#pragma unroll
    for (int i = 0; i < 4; ++i) {
        int chunk = t + i * 256;          // 0..1023
        int row = chunk >> 4, c8 = (chunk & 15) * 8;
        int n = n0 + row;
        if (n < NN) {
            u16x8 v = *(const u16x8*)&wb[row * 144 + c8];
            *(u16x8*)((unsigned short*)sag + (size_t)(bb * NN + n) * SST1 + j0 + c8) = v;
        }
    }
}

// ---------------------------------------------------------------------------
// Softmax+topk, one wave per row, zero LDS. Writes UNnormalized exp weights
// in place + per-row sum to rsum[]; pv_k applies 1/rsum in its epilogue.
// ---------------------------------------------------------------------------
__global__ __launch_bounds__(256) void smax_k(__bf16* __restrict__ sagB,
                                              const int* __restrict__ topk_p,
                                              float* __restrict__ rsum) {
    int t = threadIdx.x;
    int wid = t >> 6, lane = t & 63;
    int row = blockIdx.x * 4 + wid;
    if (row >= ROWSH) return;

    int topkv = *topk_p;
    bool selAll = (topkv <= 0);
    int kk = 0;
    if (!selAll) {
        kk = (topkv < 5) ? topkv * NN : topkv;
        if (kk > TN) kk = TN;
    }

    u16x8* src = (u16x8*)((unsigned short*)sagB + (size_t)row * SST1);
    u16x8 va[8];
#pragma unroll
    for (int ci = 0; ci < 8; ++ci) {
        int c = lane + (ci << 6);
        u16x8 v = {0, 0, 0, 0, 0, 0, 0, 0};
        if (c < 464) v = src[c];
        va[ci] = v;
    }
    // row max (values >= 0; bf16 bit order = value order; pads 0)
    int vmb = 0;
#pragma unroll
    for (int ci = 0; ci < 8; ++ci)
#pragma unroll
        for (int e = 0; e < 8; ++e) vmb = max(vmb, (int)va[ci][e]);
#pragma unroll
    for (int m = 32; m > 0; m >>= 1) vmb = max(vmb, __shfl_xor(vmb, m, 64));
    float vmax = __uint_as_float(((unsigned)vmb) << 16);

    // exact kk-th largest: smallest T with cnt(>T) < kk (ballot+popcount)
    unsigned thrb = 0;
    if (!selAll) {
        unsigned lo = 0, hi = (unsigned)vmb;
        while (lo < hi) {
            unsigned mid = (lo + hi) >> 1;
            int cnt = 0;
#pragma unroll
            for (int ci = 0; ci < 8; ++ci)
#pragma unroll
                for (int e = 0; e < 8; ++e)
                    cnt += (int)__popcll(__ballot((unsigned)va[ci][e] > mid));
            if (cnt < kk) hi = mid; else lo = mid + 1;
        }
        thrb = lo;
    }

    // exp over selected (store unnormalized exp as bf16)
    float local = 0.f;
#pragma unroll
    for (int ci = 0; ci < 8; ++ci) {
        int c = lane + (ci << 6);
        int nvv = (c < 460) ? 8 : ((c == 460) ? 4 : 0);
#pragma unroll
        for (int e = 0; e < 8; ++e) {
            unsigned u = va[ci][e];
            bool sel = selAll ? (e < nvv) : (u > thrb);
            float ev = sel ? __expf(__uint_as_float(u << 16) - vmax) : 0.f;
            local += ev;
            __bf16 eb = (__bf16)ev;
            va[ci][e] = *(unsigned short*)&eb;
        }
    }
    local = wred_sum(local);
    bool uni = !(local > 0.f);
    if (lane == 0) rsum[row] = uni ? (float)TN : local;

    if (uni) {
        __bf16 one = (__bf16)1.f, zero = (__bf16)0.f;
#pragma unroll
        for (int ci = 0; ci < 8; ++ci) {
            int c = lane + (ci << 6);
            if (c < 464) {
                int nvv = (c < 460) ? 8 : ((c == 460) ? 4 : 0);
                bf16x8 o;
#pragma unroll
                for (int e = 0; e < 8; ++e) o[e] = (e < nvv) ? one : zero;
                *(bf16x8*)&src[c] = o;
            }
        }
    } else {
#pragma unroll
        for (int ci = 0; ci < 8; ++ci) {
            int c = lane + (ci << 6);
            if (c < 464) src[c] = va[ci];
        }
    }
}

// ---------------------------------------------------------------------------
// PV GEMM, K-split 4 across blocks: hp[kq][b,n,d] = (sag[b,n,kq-chunk] @
// xnT[b,d,kq-chunk]^T) / rsum[b,n]  (+ y32 on kq==0). ffn_k sums the slabs.
// ---------------------------------------------------------------------------
__global__ __launch_bounds__(256) void pv_k(const __bf16* __restrict__ sagB,
                                            const __bf16* __restrict__ xnT,
                                            const float* __restrict__ y32,
                                            const float* __restrict__ rsum,
                                            float* __restrict__ hp) {
    int bb = blockIdx.z, kq = blockIdx.y, n0 = blockIdx.x * 16;
    int wid = threadIdx.x >> 6, lane = threadIdx.x & 63;
    int m16 = lane & 15, q4 = lane >> 4;

    int arow = min(n0 + m16, NN - 1);   // clamp: garbage rows masked at store
    const __bf16* ab  = sagB + (size_t)(bb * NN + arow) * SST1 + kq * KQ + q4 * 8;
    const __bf16* bbp = xnT + ((size_t)bb * 64 + wid * 16 + m16) * SSTR + kq * KQ + q4 * 8;

    f32x4 acc0 = {0.f, 0.f, 0.f, 0.f}, acc1 = {0.f, 0.f, 0.f, 0.f};
#pragma unroll 4
    for (int ks = 0; ks < 29; ++ks) {               // 29 * K32 = 928
        bf16x8 a = *(const bf16x8*)(ab + ks * 32);
        bf16x8 b = *(const bf16x8*)(bbp + ks * 32);
        if (ks & 1) acc1 = __builtin_amdgcn_mfma_f32_16x16x32_bf16(a, b, acc1, 0, 0, 0);
        else        acc0 = __builtin_amdgcn_mfma_f32_16x16x32_bf16(a, b, acc0, 0, 0, 0);
    }
    // C layout: row = q4*4+r (A-row = n), col = m16 (B-row = d within tile)
#pragma unroll
    for (int r = 0; r < 4; ++r) {
        int n = n0 + q4 * 4 + r;
        if (n < NN) {
            size_t o = (size_t)(bb * NN + n) * 64 + wid * 16 + m16;
            float inv = 1.f / rsum[bb * NN + n];
            float v = (acc0[r] + acc1[r]) * inv;
            if (kq == 0) v += y32[o];
            hp[(size_t)kq * HPS + o] = v;
        }
    }
}

// ---------------------------------------------------------------------------
// FFN via MFMA bf16: h = sum(hp[0..3]) -> LN -> @fc1^T+relu -> @fc2^T + h + b.
// ---------------------------------------------------------------------------
__global__ __launch_bounds__(256) void ffn_k(const float* __restrict__ hp,
                                             const float* __restrict__ g,
                                             const float* __restrict__ bln,
                                             const __bf16* __restrict__ fc1b16,
                                             const float* __restrict__ fc1b,
                                             const __bf16* __restrict__ fc2b16,
                                             const float* __restrict__ fc2b,
                                             float* __restrict__ out) {
    __shared__ __bf16 zb[16 * 68];
    __shared__ __bf16 ab[16 * 264];
    int t = threadIdx.x, r0 = blockIdx.x * 16;
    int wid = t >> 6, lane = t & 63;
    int m16 = lane & 15, q4 = lane >> 4;

#pragma unroll
    for (int q = 0; q < 4; ++q) {
        int rl = wid * 4 + q;
        size_t i = (size_t)(r0 + rl) * 64 + lane;
        float val = hp[i] + hp[HPS + i] + hp[2 * HPS + i] + hp[3 * HPS + i];
        float mu  = wred_sum(val) * (1.f / 64.f);
        float dv  = val - mu;
        float var = wred_sum(dv * dv) * (1.f / 64.f);
        zb[rl * 68 + lane] = (__bf16)(dv * rsqrtf(var + 1e-5f) * g[lane] + bln[lane]);
    }
    __syncthreads();

    bf16x8 a0 = *(const bf16x8*)&zb[m16 * 68 + q4 * 8];
    bf16x8 a1 = *(const bf16x8*)&zb[m16 * 68 + 32 + q4 * 8];
#pragma unroll
    for (int jt2 = 0; jt2 < 4; ++jt2) {
        int j0t = (wid * 4 + jt2) * 16;
        const __bf16* bp = fc1b16 + (size_t)(j0t + m16) * 64 + q4 * 8;
        f32x4 c = {0.f, 0.f, 0.f, 0.f};
        c = __builtin_amdgcn_mfma_f32_16x16x32_bf16(a0, *(const bf16x8*)bp, c, 0, 0, 0);
        c = __builtin_amdgcn_mfma_f32_16x16x32_bf16(a1, *(const bf16x8*)(bp + 32), c, 0, 0, 0);
        int j = j0t + m16;
        float bias = fc1b[j];
#pragma unroll
        for (int r = 0; r < 4; ++r)
            ab[(q4 * 4 + r) * 264 + j] = (__bf16)fmaxf(c[r] + bias, 0.f);
    }
    __syncthreads();

    f32x4 c2a = {0.f, 0.f, 0.f, 0.f}, c2b = {0.f, 0.f, 0.f, 0.f};
    const __bf16* b2p = fc2b16 + (size_t)(wid * 16 + m16) * 256 + q4 * 8;
#pragma unroll
    for (int k8 = 0; k8 < 8; k8 += 2) {
        bf16x8 aa0 = *(const bf16x8*)&ab[m16 * 264 + k8 * 32 + q4 * 8];
        bf16x8 aa1 = *(const bf16x8*)&ab[m16 * 264 + (k8 + 1) * 32 + q4 * 8];
        c2a = __builtin_amdgcn_mfma_f32_16x16x32_bf16(aa0, *(const bf16x8*)(b2p + k8 * 32), c2a, 0, 0, 0);
        c2b = __builtin_amdgcn_mfma_f32_16x16x32_bf16(aa1, *(const bf16x8*)(b2p + (k8 + 1) * 32), c2b, 0, 0, 0);
    }
    int d = wid * 16 + m16;
    float bias2 = fc2b[d];
#pragma unroll
    for (int r = 0; r < 4; ++r) {
        size_t row = (size_t)(r0 + q4 * 4 + r);
        size_t o = row * 64 + d;
        float hsum = hp[o] + hp[HPS + o] + hp[2 * HPS + o] + hp[3 * HPS + o];
        out[o] = hsum + c2a[r] + c2b[r] + bias2;
    }
}

extern "C" void kernel_launch(void* const* d_in, const int* in_sizes, int n_in,
                              void* d_out, int out_size, void* d_ws, size_t ws_size,
                              hipStream_t stream) {
    const float* x    = (const float*)d_in[0];
    const float* stg  = (const float*)d_in[1];
    const int*   topk = (const int*)d_in[2];
    const float* qw   = (const float*)d_in[3];
    const float* qb   = (const float*)d_in[4];
    const float* kw   = (const float*)d_in[5];
    const float* kb   = (const float*)d_in[6];
    const float* lng  = (const float*)d_in[7];
    const float* lnb  = (const float*)d_in[8];
    const float* flng = (const float*)d_in[9];
    const float* flnb = (const float*)d_in[10];
    const float* fc1w = (const float*)d_in[11];
    const float* fc1b = (const float*)d_in[12];
    const float* fc2w = (const float*)d_in[13];
    const float* fc2b = (const float*)d_in[14];
    float* out = (float*)d_out;

    float* ws = (float*)d_ws;
    __bf16* xnb = (__bf16*)ws;                 // ROWSX*64 bf16 = 1,886,208 f
    float* p1   = ws + 1886208;
    __bf16* xnT = (__bf16*)p1;                 // 16*64*3840 bf16 = 1,966,080 f
    float* p2   = p1 + 1966080;
    __bf16* qtb = (__bf16*)p2;                 // 4928*64 bf16 = 157,696 f
    float* y32  = p2 + 157696;                 // 314,368 f
    float* cq   = y32 + 314368;                // 4,928 f
    float* M    = cq + 4928;                   // 4,096
    float* b2   = M + 4096;                    // 64
    float* vv   = b2 + 64;                     // 64
    float* cc   = vv + 64;                     // 16
    __bf16* fc1b16 = (__bf16*)(cc + 16);       // 8,192 f
    __bf16* fc2b16 = (__bf16*)((float*)fc1b16 + 8192);  // 8,192 f
    __bf16* sag = (__bf16*)((float*)fc2b16 + 8192);     // ROWSH*3712 bf16 = 9,116,672 f
    float* hp   = (float*)sag + 9116672;       // 4*314,368 f (K-split partials)
    float* rsum = hp + 4 * HPS;                // 4,928 f

    fold_k<<<64, 64, 0, stream>>>(qw, qb, kw, kb, M, b2, vv, cc);
    wconv_k<<<128, 256, 0, stream>>>(fc1w, fc2w, fc1b16, fc2b16);
    lnt_k<<<dim3(58, BB), 256, 0, stream>>>(x, lng, lnb, xnb, xnT, y32);
    qt_k<<<(ROWSH + 3) / 4, 256, 0, stream>>>(y32, M, b2, vv, cc, qtb, cq);
    score_k<<<dim3((TN + 127) / 128, (NN + 63) / 64, BB), 256, 0, stream>>>(qtb, cq, xnb, stg, sag);
    smax_k<<<(ROWSH + 3) / 4, 256, 0, stream>>>(sag, topk, rsum);
    pv_k<<<dim3((NN + 15) / 16, 4, BB), 256, 0, stream>>>(sag, xnT, y32, rsum, hp);
    ffn_k<<<ROWSH / 16, 256, 0, stream>>>(hp, flng, flnb, fc1b16, fc1b, fc2b16, fc2b, out);
}

// Round 4
// 256.484 us; speedup vs baseline: 1.1399x; 1.0386x over previous
//
#include <hip/hip_runtime.h>

typedef __bf16 bf16x8 __attribute__((ext_vector_type(8)));
typedef float  f32x4  __attribute__((ext_vector_type(4)));
typedef unsigned short u16x8 __attribute__((ext_vector_type(8)));
typedef unsigned short u16x4 __attribute__((ext_vector_type(4)));

// Problem constants
constexpr int BB    = 16;
constexpr int TT    = 12;
constexpr int NN    = 307;
constexpr int TN    = TT * NN;        // 3684
constexpr int ROWSX = BB * TT * NN;   // 58944
constexpr int ROWSH = BB * NN;        // 4912
constexpr int SST1  = 3712;           // sag row stride (464 x b128 chunks)
constexpr int SSTR  = 3840;           // xnT row stride
constexpr int HPS   = ROWSH * 64;     // hp slab stride (314368 floats)
constexpr int KQ    = 928;            // pv K-split chunk (3712/4)
constexpr int WBS   = 152;            // score LDS stride: 76 dw = 12 mod 32 -> 2-way max
constexpr float SCALE = 0.125f;

__device__ __forceinline__ float wred_sum(float v) {
#pragma unroll
    for (int m = 32; m > 0; m >>= 1) v += __shfl_xor(v, m, 64);
    return v;
}

// ---------------------------------------------------------------------------
// Fold q/k projections: dg = q.k = qt.x_ + c
// ---------------------------------------------------------------------------
__global__ void fold_k(const float* __restrict__ qw, const float* __restrict__ qb,
                       const float* __restrict__ kw, const float* __restrict__ kb,
                       float* __restrict__ M, float* __restrict__ b2,
                       float* __restrict__ vv, float* __restrict__ cc) {
    int e = blockIdx.x, d = threadIdx.x;
    float acc = 0.f;
    for (int dp = 0; dp < 64; ++dp) acc += qw[dp * 64 + e] * kw[dp * 64 + d];
    M[e * 64 + d] = acc;
    float vp = wred_sum(qw[d * 64 + e] * kb[d]);
    if (d == 0) vv[e] = vp;
    if (e == 0) {
        float b = 0.f;
        for (int dp = 0; dp < 64; ++dp) b += qb[dp] * kw[dp * 64 + d];
        b2[d] = b;
        float cp = wred_sum(qb[d] * kb[d]);
        if (d == 0) *cc = cp;
    }
}

// ---------------------------------------------------------------------------
// fc1w/fc2w fp32 -> bf16
// ---------------------------------------------------------------------------
__global__ void wconv_k(const float* __restrict__ fc1w, const float* __restrict__ fc2w,
                        __bf16* __restrict__ fc1b16, __bf16* __restrict__ fc2b16) {
    int i = blockIdx.x * 256 + threadIdx.x;
    if (i < 16384) fc1b16[i] = (__bf16)fc1w[i];
    else fc2b16[i - 16384] = (__bf16)fc2w[i - 16384];
}

// ---------------------------------------------------------------------------
// LayerNorm -> xnb (bf16) + y32 (fp32, t==11 slab). 1 row/wave, 14736 blocks
// (max parallelism -- the fused lnt variant serialized 16 rows/wave and
// regressed ~6us; reverted).
// ---------------------------------------------------------------------------
__global__ __launch_bounds__(256) void ln_k(const float* __restrict__ x,
                                            const float* __restrict__ g,
                                            const float* __restrict__ b,
                                            __bf16* __restrict__ xnb,
                                            float* __restrict__ y32) {
    int w = threadIdx.x >> 6, l = threadIdx.x & 63;
    int r = blockIdx.x * 4 + w;
    if (r >= ROWSX) return;
    float val = x[r * 64 + l];
    float mu  = wred_sum(val) * (1.f / 64.f);
    float dv  = val - mu;
    float var = wred_sum(dv * dv) * (1.f / 64.f);
    float xv  = dv * rsqrtf(var + 1e-5f) * g[l] + b[l];
    xnb[(size_t)r * 64 + l] = (__bf16)xv;
    int t = (r / NN) % TT;
    if (t == TT - 1) {
        int bbv = r / (NN * TT), n = r % NN;
        y32[(bbv * NN + n) * 64 + l] = xv;
    }
}

// ---------------------------------------------------------------------------
// Transpose xnb[b,j,d] -> xnT[b,d,j] (stride SSTR; j>=TN zero within tiles)
// ---------------------------------------------------------------------------
__global__ __launch_bounds__(256) void t_k(const __bf16* __restrict__ xnb,
                                           __bf16* __restrict__ xnT) {
    __shared__ unsigned short tile[64][65];
    int bb = blockIdx.y, j0 = blockIdx.x * 64, t = threadIdx.x;
    const unsigned short* src = (const unsigned short*)xnb;
    unsigned short* dst = (unsigned short*)xnT;
#pragma unroll
    for (int i = 0; i < 16; ++i) {
        int f = t + 256 * i, jr = f >> 6, dc = f & 63;
        int j = j0 + jr;
        tile[jr][dc] = (j < TN) ? src[((size_t)bb * TN + j) * 64 + dc] : (unsigned short)0;
    }
    __syncthreads();
#pragma unroll
    for (int i = 0; i < 16; ++i) {
        int f = t + 256 * i, d = f >> 6, jj = f & 63;
        dst[((size_t)bb * 64 + d) * SSTR + j0 + jj] = tile[jj][d];
    }
}

// ---------------------------------------------------------------------------
// qt[row] = y_ @ M + b2 (bf16);  cq[row] = y_.v + cc
// ---------------------------------------------------------------------------
__global__ __launch_bounds__(256) void qt_k(const float* __restrict__ y32,
                                            const float* __restrict__ M,
                                            const float* __restrict__ b2,
                                            const float* __restrict__ vv,
                                            const float* __restrict__ ccp,
                                            __bf16* __restrict__ qtb,
                                            float* __restrict__ cq) {
    int w = threadIdx.x >> 6, l = threadIdx.x & 63;
    int rr = blockIdx.x * 4 + w;
    if (rr >= ROWSH) return;
    float y = y32[rr * 64 + l];
    float acc = b2[l];
#pragma unroll
    for (int e = 0; e < 64; ++e) acc += __shfl(y, e, 64) * M[e * 64 + l];
    qtb[(size_t)rr * 64 + l] = (__bf16)acc;
    float cp = wred_sum(y * vv[l]);
    if (l == 0) cq[rr] = cp + *ccp;
}

// ---------------------------------------------------------------------------
// Score GEMM via MFMA. v4: register-prefetch stg float4 + cq BEFORE the
// fragment loads/MFMA (one latency exposure, ~20 loads in flight; VGPR
// licensed to 128 via launch_bounds(256,4)). LDS stride 144->152 (76 dw =
// 12 mod 32): u16x4 scatter is 2-way max (was 4-way, 1.03M conflicts).
// ---------------------------------------------------------------------------
__global__ __launch_bounds__(256, 4) void score_k(const __bf16* __restrict__ qtb,
                                                  const float* __restrict__ cq,
                                                  const __bf16* __restrict__ xnb,
                                                  const float* __restrict__ stg,
                                                  __bf16* __restrict__ sag) {
    __shared__ unsigned short wb[64 * WBS];   // 19.5 KB  [n(64)][j(128+pad)]
    int bb = blockIdx.z, n0 = blockIdx.y * 64, j0 = blockIdx.x * 128;
    int t = threadIdx.x;
    int w = t >> 6, lane = t & 63;
    int m16 = lane & 15, q4 = lane >> 4;

    // ---- prefetch stg tiles (8 x float4) + cq (4) into registers ----
    const float* stgb = stg + (size_t)bb * NN * TN;
    float4 sv[4][2];
    float cn[4];
#pragma unroll
    for (int nt = 0; nt < 4; ++nt) {
        int n = n0 + nt * 16 + m16;
        const float* srow = stgb + (size_t)min(n, NN - 1) * TN;
#pragma unroll
        for (int jj = 0; jj < 2; ++jj) {
            int jb = j0 + (w * 2 + jj) * 16 + q4 * 4;   // 4-aligned; TN is 4-aligned
            float4 s4 = {0.f, 0.f, 0.f, 0.f};
            if (jb < TN) s4 = *(const float4*)(srow + jb);
            sv[nt][jj] = s4;
        }
        int nc = n0 + nt * 16 + m16;   // cq indexed by C-col = m16 within nt tile
        cn[nt] = 0.f;
    }
    // cq is per C-col (n = n0 + nt*16 + m16): load all 4
#pragma unroll
    for (int nt = 0; nt < 4; ++nt) {
        int n = n0 + nt * 16 + m16;
        cn[nt] = (n < NN) ? cq[bb * NN + n] : 0.f;
    }

    // ---- A fragments: xnb rows j (2 jt tiles per wave) ----
    bf16x8 a[2][2];
#pragma unroll
    for (int jj = 0; jj < 2; ++jj) {
        const bf16x8* ap = (const bf16x8*)(xnb + ((size_t)bb * TN + j0 + (w * 2 + jj) * 16 + m16) * 64);
        a[jj][0] = ap[q4];
        a[jj][1] = ap[q4 + 4];
    }

    // ---- MFMA: C[j_local][n_local], 2 jt x 4 nt tiles per wave ----
    f32x4 acc[2][4];
#pragma unroll
    for (int nt = 0; nt < 4; ++nt) {
        const bf16x8* bp = (const bf16x8*)(qtb + ((size_t)bb * NN + n0 + nt * 16 + m16) * 64);
        bf16x8 b0 = bp[q4], b1 = bp[q4 + 4];
#pragma unroll
        for (int jj = 0; jj < 2; ++jj) {
            f32x4 c = {0.f, 0.f, 0.f, 0.f};
            c = __builtin_amdgcn_mfma_f32_16x16x32_bf16(a[jj][0], b0, c, 0, 0, 0);
            c = __builtin_amdgcn_mfma_f32_16x16x32_bf16(a[jj][1], b1, c, 0, 0, 0);
            acc[jj][nt] = c;
        }
    }

    // ---- epilogue: sigmoid(dg)*stg*scale from registers only ----
#pragma unroll
    for (int nt = 0; nt < 4; ++nt) {
#pragma unroll
        for (int jj = 0; jj < 2; ++jj) {
            int jb = j0 + (w * 2 + jj) * 16 + q4 * 4;
            float svv[4] = {sv[nt][jj].x, sv[nt][jj].y, sv[nt][jj].z, sv[nt][jj].w};
            u16x4 hw;
#pragma unroll
            for (int r = 0; r < 4; ++r) {
                float dg = (acc[jj][nt][r] + cn[nt]) * SCALE;
                float s  = 1.f / (1.f + __expf(-dg));
                float wv = (jb + r < TN) ? s * svv[r] * SCALE : 0.f;
                __bf16 wb16 = (__bf16)wv;
                hw[r] = *(unsigned short*)&wb16;
            }
            *(u16x4*)&wb[(nt * 16 + m16) * WBS + (w * 2 + jj) * 16 + q4 * 4] = hw;
        }
    }
    __syncthreads();

    // ---- coalesced b128 stores ----
#pragma unroll
    for (int i = 0; i < 4; ++i) {
        int chunk = t + i * 256;          // 0..1023
        int row = chunk >> 4, c8 = (chunk & 15) * 8;
        int n = n0 + row;
        if (n < NN) {
            u16x8 v = *(const u16x8*)&wb[row * WBS + c8];
            *(u16x8*)((unsigned short*)sag + (size_t)(bb * NN + n) * SST1 + j0 + c8) = v;
        }
    }
}

// ---------------------------------------------------------------------------
// Softmax+topk, one wave per row, zero LDS. Writes UNnormalized exp weights
// in place + per-row sum to rsum[]; pv_k applies 1/rsum in its epilogue.
// ---------------------------------------------------------------------------
__global__ __launch_bounds__(256) void smax_k(__bf16* __restrict__ sagB,
                                              const int* __restrict__ topk_p,
                                              float* __restrict__ rsum) {
    int t = threadIdx.x;
    int wid = t >> 6, lane = t & 63;
    int row = blockIdx.x * 4 + wid;
    if (row >= ROWSH) return;

    int topkv = *topk_p;
    bool selAll = (topkv <= 0);
    int kk = 0;
    if (!selAll) {
        kk = (topkv < 5) ? topkv * NN : topkv;
        if (kk > TN) kk = TN;
    }

    u16x8* src = (u16x8*)((unsigned short*)sagB + (size_t)row * SST1);
    u16x8 va[8];
#pragma unroll
    for (int ci = 0; ci < 8; ++ci) {
        int c = lane + (ci << 6);
        u16x8 v = {0, 0, 0, 0, 0, 0, 0, 0};
        if (c < 464) v = src[c];
        va[ci] = v;
    }
    // row max (values >= 0; bf16 bit order = value order; pads 0)
    int vmb = 0;
#pragma unroll
    for (int ci = 0; ci < 8; ++ci)
#pragma unroll
        for (int e = 0; e < 8; ++e) vmb = max(vmb, (int)va[ci][e]);
#pragma unroll
    for (int m = 32; m > 0; m >>= 1) vmb = max(vmb, __shfl_xor(vmb, m, 64));
    float vmax = __uint_as_float(((unsigned)vmb) << 16);

    // exact kk-th largest: smallest T with cnt(>T) < kk (ballot+popcount)
    unsigned thrb = 0;
    if (!selAll) {
        unsigned lo = 0, hi = (unsigned)vmb;
        while (lo < hi) {
            unsigned mid = (lo + hi) >> 1;
            int cnt = 0;
#pragma unroll
            for (int ci = 0; ci < 8; ++ci)
#pragma unroll
                for (int e = 0; e < 8; ++e)
                    cnt += (int)__popcll(__ballot((unsigned)va[ci][e] > mid));
            if (cnt < kk) hi = mid; else lo = mid + 1;
        }
        thrb = lo;
    }

    // exp over selected (store unnormalized exp as bf16)
    float local = 0.f;
#pragma unroll
    for (int ci = 0; ci < 8; ++ci) {
        int c = lane + (ci << 6);
        int nvv = (c < 460) ? 8 : ((c == 460) ? 4 : 0);
#pragma unroll
        for (int e = 0; e < 8; ++e) {
            unsigned u = va[ci][e];
            bool sel = selAll ? (e < nvv) : (u > thrb);
            float ev = sel ? __expf(__uint_as_float(u << 16) - vmax) : 0.f;
            local += ev;
            __bf16 eb = (__bf16)ev;
            va[ci][e] = *(unsigned short*)&eb;
        }
    }
    local = wred_sum(local);
    bool uni = !(local > 0.f);
    if (lane == 0) rsum[row] = uni ? (float)TN : local;

    if (uni) {
        __bf16 one = (__bf16)1.f, zero = (__bf16)0.f;
#pragma unroll
        for (int ci = 0; ci < 8; ++ci) {
            int c = lane + (ci << 6);
            if (c < 464) {
                int nvv = (c < 460) ? 8 : ((c == 460) ? 4 : 0);
                bf16x8 o;
#pragma unroll
                for (int e = 0; e < 8; ++e) o[e] = (e < nvv) ? one : zero;
                *(bf16x8*)&src[c] = o;
            }
        }
    } else {
#pragma unroll
        for (int ci = 0; ci < 8; ++ci) {
            int c = lane + (ci << 6);
            if (c < 464) src[c] = va[ci];
        }
    }
}

// ---------------------------------------------------------------------------
// PV GEMM, K-split 4 across blocks: hp[kq][b,n,d] = (sag[b,n,kq-chunk] @
// xnT[b,d,kq-chunk]^T) / rsum[b,n]  (+ y32 on kq==0). ffn_k sums the slabs.
// ---------------------------------------------------------------------------
__global__ __launch_bounds__(256) void pv_k(const __bf16* __restrict__ sagB,
                                            const __bf16* __restrict__ xnT,
                                            const float* __restrict__ y32,
                                            const float* __restrict__ rsum,
                                            float* __restrict__ hp) {
    int bb = blockIdx.z, kq = blockIdx.y, n0 = blockIdx.x * 16;
    int wid = threadIdx.x >> 6, lane = threadIdx.x & 63;
    int m16 = lane & 15, q4 = lane >> 4;

    int arow = min(n0 + m16, NN - 1);   // clamp: garbage rows masked at store
    const __bf16* ab  = sagB + (size_t)(bb * NN + arow) * SST1 + kq * KQ + q4 * 8;
    const __bf16* bbp = xnT + ((size_t)bb * 64 + wid * 16 + m16) * SSTR + kq * KQ + q4 * 8;

    f32x4 acc0 = {0.f, 0.f, 0.f, 0.f}, acc1 = {0.f, 0.f, 0.f, 0.f};
#pragma unroll 4
    for (int ks = 0; ks < 29; ++ks) {               // 29 * K32 = 928
        bf16x8 a = *(const bf16x8*)(ab + ks * 32);
        bf16x8 b = *(const bf16x8*)(bbp + ks * 32);
        if (ks & 1) acc1 = __builtin_amdgcn_mfma_f32_16x16x32_bf16(a, b, acc1, 0, 0, 0);
        else        acc0 = __builtin_amdgcn_mfma_f32_16x16x32_bf16(a, b, acc0, 0, 0, 0);
    }
    // C layout: row = q4*4+r (A-row = n), col = m16 (B-row = d within tile)
#pragma unroll
    for (int r = 0; r < 4; ++r) {
        int n = n0 + q4 * 4 + r;
        if (n < NN) {
            size_t o = (size_t)(bb * NN + n) * 64 + wid * 16 + m16;
            float inv = 1.f / rsum[bb * NN + n];
            float v = (acc0[r] + acc1[r]) * inv;
            if (kq == 0) v += y32[o];
            hp[(size_t)kq * HPS + o] = v;
        }
    }
}

// ---------------------------------------------------------------------------
// FFN via MFMA bf16: h = sum(hp[0..3]) -> LN -> @fc1^T+relu -> @fc2^T + h + b.
// ---------------------------------------------------------------------------
__global__ __launch_bounds__(256) void ffn_k(const float* __restrict__ hp,
                                             const float* __restrict__ g,
                                             const float* __restrict__ bln,
                                             const __bf16* __restrict__ fc1b16,
                                             const float* __restrict__ fc1b,
                                             const __bf16* __restrict__ fc2b16,
                                             const float* __restrict__ fc2b,
                                             float* __restrict__ out) {
    __shared__ __bf16 zb[16 * 68];
    __shared__ __bf16 ab[16 * 264];
    int t = threadIdx.x, r0 = blockIdx.x * 16;
    int wid = t >> 6, lane = t & 63;
    int m16 = lane & 15, q4 = lane >> 4;

#pragma unroll
    for (int q = 0; q < 4; ++q) {
        int rl = wid * 4 + q;
        size_t i = (size_t)(r0 + rl) * 64 + lane;
        float val = hp[i] + hp[HPS + i] + hp[2 * HPS + i] + hp[3 * HPS + i];
        float mu  = wred_sum(val) * (1.f / 64.f);
        float dv  = val - mu;
        float var = wred_sum(dv * dv) * (1.f / 64.f);
        zb[rl * 68 + lane] = (__bf16)(dv * rsqrtf(var + 1e-5f) * g[lane] + bln[lane]);
    }
    __syncthreads();

    bf16x8 a0 = *(const bf16x8*)&zb[m16 * 68 + q4 * 8];
    bf16x8 a1 = *(const bf16x8*)&zb[m16 * 68 + 32 + q4 * 8];
#pragma unroll
    for (int jt2 = 0; jt2 < 4; ++jt2) {
        int j0t = (wid * 4 + jt2) * 16;
        const __bf16* bp = fc1b16 + (size_t)(j0t + m16) * 64 + q4 * 8;
        f32x4 c = {0.f, 0.f, 0.f, 0.f};
        c = __builtin_amdgcn_mfma_f32_16x16x32_bf16(a0, *(const bf16x8*)bp, c, 0, 0, 0);
        c = __builtin_amdgcn_mfma_f32_16x16x32_bf16(a1, *(const bf16x8*)(bp + 32), c, 0, 0, 0);
        int j = j0t + m16;
        float bias = fc1b[j];
#pragma unroll
        for (int r = 0; r < 4; ++r)
            ab[(q4 * 4 + r) * 264 + j] = (__bf16)fmaxf(c[r] + bias, 0.f);
    }
    __syncthreads();

    f32x4 c2a = {0.f, 0.f, 0.f, 0.f}, c2b = {0.f, 0.f, 0.f, 0.f};
    const __bf16* b2p = fc2b16 + (size_t)(wid * 16 + m16) * 256 + q4 * 8;
#pragma unroll
    for (int k8 = 0; k8 < 8; k8 += 2) {
        bf16x8 aa0 = *(const bf16x8*)&ab[m16 * 264 + k8 * 32 + q4 * 8];
        bf16x8 aa1 = *(const bf16x8*)&ab[m16 * 264 + (k8 + 1) * 32 + q4 * 8];
        c2a = __builtin_amdgcn_mfma_f32_16x16x32_bf16(aa0, *(const bf16x8*)(b2p + k8 * 32), c2a, 0, 0, 0);
        c2b = __builtin_amdgcn_mfma_f32_16x16x32_bf16(aa1, *(const bf16x8*)(b2p + (k8 + 1) * 32), c2b, 0, 0, 0);
    }
    int d = wid * 16 + m16;
    float bias2 = fc2b[d];
#pragma unroll
    for (int r = 0; r < 4; ++r) {
        size_t row = (size_t)(r0 + q4 * 4 + r);
        size_t o = row * 64 + d;
        float hsum = hp[o] + hp[HPS + o] + hp[2 * HPS + o] + hp[3 * HPS + o];
        out[o] = hsum + c2a[r] + c2b[r] + bias2;
    }
}

extern "C" void kernel_launch(void* const* d_in, const int* in_sizes, int n_in,
                              void* d_out, int out_size, void* d_ws, size_t ws_size,
                              hipStream_t stream) {
    const float* x    = (const float*)d_in[0];
    const float* stg  = (const float*)d_in[1];
    const int*   topk = (const int*)d_in[2];
    const float* qw   = (const float*)d_in[3];
    const float* qb   = (const float*)d_in[4];
    const float* kw   = (const float*)d_in[5];
    const float* kb   = (const float*)d_in[6];
    const float* lng  = (const float*)d_in[7];
    const float* lnb  = (const float*)d_in[8];
    const float* flng = (const float*)d_in[9];
    const float* flnb = (const float*)d_in[10];
    const float* fc1w = (const float*)d_in[11];
    const float* fc1b = (const float*)d_in[12];
    const float* fc2w = (const float*)d_in[13];
    const float* fc2b = (const float*)d_in[14];
    float* out = (float*)d_out;

    float* ws = (float*)d_ws;
    __bf16* xnb = (__bf16*)ws;                 // ROWSX*64 bf16 = 1,886,208 f
    float* p1   = ws + 1886208;
    __bf16* xnT = (__bf16*)p1;                 // 16*64*3840 bf16 = 1,966,080 f
    float* p2   = p1 + 1966080;
    __bf16* qtb = (__bf16*)p2;                 // 4928*64 bf16 = 157,696 f
    float* y32  = p2 + 157696;                 // 314,368 f
    float* cq   = y32 + 314368;                // 4,928 f
    float* M    = cq + 4928;                   // 4,096
    float* b2   = M + 4096;                    // 64
    float* vv   = b2 + 64;                     // 64
    float* cc   = vv + 64;                     // 16
    __bf16* fc1b16 = (__bf16*)(cc + 16);       // 8,192 f
    __bf16* fc2b16 = (__bf16*)((float*)fc1b16 + 8192);  // 8,192 f
    __bf16* sag = (__bf16*)((float*)fc2b16 + 8192);     // ROWSH*3712 bf16 = 9,116,672 f
    float* hp   = (float*)sag + 9116672;       // 4*314,368 f (K-split partials)
    float* rsum = hp + 4 * HPS;                // 4,928 f

    fold_k<<<64, 64, 0, stream>>>(qw, qb, kw, kb, M, b2, vv, cc);
    wconv_k<<<128, 256, 0, stream>>>(fc1w, fc2w, fc1b16, fc2b16);
    ln_k<<<(ROWSX + 3) / 4, 256, 0, stream>>>(x, lng, lnb, xnb, y32);
    t_k<<<dim3((TN + 63) / 64, BB), 256, 0, stream>>>(xnb, xnT);
    qt_k<<<(ROWSH + 3) / 4, 256, 0, stream>>>(y32, M, b2, vv, cc, qtb, cq);
    score_k<<<dim3((TN + 127) / 128, (NN + 63) / 64, BB), 256, 0, stream>>>(qtb, cq, xnb, stg, sag);
    smax_k<<<(ROWSH + 3) / 4, 256, 0, stream>>>(sag, topk, rsum);
    pv_k<<<dim3((NN + 15) / 16, 4, BB), 256, 0, stream>>>(sag, xnT, y32, rsum, hp);
    ffn_k<<<ROWSH / 16, 256, 0, stream>>>(hp, flng, flnb, fc1b16, fc1b, fc2b16, fc2b, out);
}